// Round 2
// baseline (697.053 us; speedup 1.0000x reference)
//
#include <hip/hip_runtime.h>
#include <hip/hip_bf16.h>

#define EMBED 1024
#define HEADS 16
#define HD 64
#define NVTOK 4096
#define NLTOK 256
#define BATCH 4
#define QSCALE 0.25f   // HEADS**-0.5

typedef __hip_bfloat16 bf16;
typedef __attribute__((ext_vector_type(8))) short bf16x8;
typedef __attribute__((ext_vector_type(4))) float floatx4;

#define MFMA(a, b, c) __builtin_amdgcn_mfma_f32_16x16x32_bf16((a), (b), (c), 0, 0, 0)

static __device__ __forceinline__ short f2bs(float x) {
  bf16 h = __float2bfloat16(x);
  return *reinterpret_cast<short*>(&h);
}
static __device__ __forceinline__ float b2f(bf16 x) { return __bfloat162float(x); }

// ---------------------------------------------------------------------------
// Input dtype detector. For bf16-packed data, bits[14:7] of each u32 are the
// low element's exponent field (clustered in [110,140] for ~N(0,1) data);
// for fp32 they are mid-mantissa bits (uniform). flag[0]=1 => fp32 inputs.
// flag[1] is a constant 0 used as "bf16 output" selector for internal GEMMs.
// ---------------------------------------------------------------------------
__global__ void detect_dtype(const unsigned* __restrict__ v, int* __restrict__ flag) {
  __shared__ int cnt;
  if (threadIdx.x == 0) cnt = 0;
  __syncthreads();
  unsigned u = v[threadIdx.x];
  int mid = (int)((u >> 7) & 0xFF);
  if (mid >= 110 && mid <= 140) atomicAdd(&cnt, 1);
  __syncthreads();
  if (threadIdx.x == 0) {
    flag[0] = (cnt < 192) ? 1 : 0;
    flag[1] = 0;
  }
}

// ---------------------------------------------------------------------------
// Convert input tensor to bf16 (either cast from fp32 or plain copy).
// ---------------------------------------------------------------------------
__global__ void convert_to_bf16(const void* __restrict__ src, bf16* __restrict__ dst,
                                int n, const int* __restrict__ flag) {
  int i = blockIdx.x * 256 + threadIdx.x;
  if (i >= n) return;
  if (flag[0]) dst[i] = __float2bfloat16(((const float*)src)[i]);
  else         dst[i] = ((const bf16*)src)[i];
}

// Convert + transpose weights: src [R][C] -> dst [C][R] bf16.
__global__ void convert_transpose(const void* __restrict__ src, bf16* __restrict__ dst,
                                  int R, int C, const int* __restrict__ flag) {
  int idx = blockIdx.x * 256 + threadIdx.x;
  if (idx >= R * C) return;
  int r = idx / C, c = idx - r * C;
  float x = flag[0] ? ((const float*)src)[idx] : b2f(((const bf16*)src)[idx]);
  dst[c * R + r] = __float2bfloat16(x);
}

// ---------------------------------------------------------------------------
// val_l per-head transpose: vl [B*NL][E] -> vlT [B*H][HD][NL]
// ---------------------------------------------------------------------------
__global__ void transpose_vl_heads(const bf16* __restrict__ vl, bf16* __restrict__ vlT) {
  int idx = blockIdx.x * 256 + threadIdx.x;  // 64bh * 64d * 256nl
  if (idx >= 64 * 64 * 256) return;
  int nl = idx & 255;
  int d  = (idx >> 8) & 63;
  int bh = idx >> 14;
  int b = bh >> 4, h = bh & 15;
  vlT[idx] = vl[((size_t)b * NLTOK + nl) * EMBED + h * HD + d];
}

// ---------------------------------------------------------------------------
// NT GEMM: C[M][N] = (A[M][K] @ Bt[N][K]^T + bias) * alpha, bf16 in.
// Output: bf16 (outf[0]==0) or fp32 (outf[0]==1), at element offset coff.
// 128x128 tile, BK=32, 4 waves each 64x64. M%128==0, N%128==0, K%32==0.
// ---------------------------------------------------------------------------
__global__ __launch_bounds__(256) void gemm_nt(
    const bf16* __restrict__ A, const bf16* __restrict__ Bt,
    const bf16* __restrict__ bias, void* __restrict__ Cout, long long coff,
    int M, int N, int K, float alpha, const int* __restrict__ outf) {
  __shared__ short As[128 * 40];
  __shared__ short Bs[128 * 40];
  const int f32o = outf[0];
  const int tid = threadIdx.x;
  const int wave = tid >> 6, lane = tid & 63;
  const int bm = blockIdx.x * 128, bn = blockIdx.y * 128;
  const int wr = (wave & 1) * 64, wc = (wave >> 1) * 64;
  const int rl = lane & 15, kg = (lane >> 4) * 8;
  const int sr = tid >> 1, sko = (tid & 1) * 16;
  const short* Ag = (const short*)A + (size_t)(bm + sr) * K + sko;
  const short* Bg = (const short*)Bt + (size_t)(bn + sr) * K + sko;

  floatx4 acc[4][4];
#pragma unroll
  for (int i = 0; i < 4; i++)
#pragma unroll
    for (int j = 0; j < 4; j++) acc[i][j] = (floatx4){0.f, 0.f, 0.f, 0.f};

  for (int k0 = 0; k0 < K; k0 += 32) {
    __syncthreads();
    *(bf16x8*)&As[sr * 40 + sko]     = *(const bf16x8*)(Ag + k0);
    *(bf16x8*)&As[sr * 40 + sko + 8] = *(const bf16x8*)(Ag + k0 + 8);
    *(bf16x8*)&Bs[sr * 40 + sko]     = *(const bf16x8*)(Bg + k0);
    *(bf16x8*)&Bs[sr * 40 + sko + 8] = *(const bf16x8*)(Bg + k0 + 8);
    __syncthreads();
    bf16x8 af[4], bfr[4];
#pragma unroll
    for (int i = 0; i < 4; i++) af[i]  = *(const bf16x8*)&As[(wr + i * 16 + rl) * 40 + kg];
#pragma unroll
    for (int j = 0; j < 4; j++) bfr[j] = *(const bf16x8*)&Bs[(wc + j * 16 + rl) * 40 + kg];
#pragma unroll
    for (int i = 0; i < 4; i++)
#pragma unroll
      for (int j = 0; j < 4; j++) acc[i][j] = MFMA(af[i], bfr[j], acc[i][j]);
  }

  const int rg = (lane >> 4) * 4;
#pragma unroll
  for (int j = 0; j < 4; j++) {
    int col = bn + wc + j * 16 + rl;
    float bv = b2f(bias[col]);
#pragma unroll
    for (int i = 0; i < 4; i++) {
#pragma unroll
      for (int r = 0; r < 4; r++) {
        int row = bm + wr + i * 16 + rg + r;
        float val = (acc[i][j][r] + bv) * alpha;
        long long idx = coff + (long long)row * N + col;
        if (f32o) ((float*)Cout)[idx] = val;
        else      ((bf16*)Cout)[idx]  = __float2bfloat16(val);
      }
    }
  }
}

// ---------------------------------------------------------------------------
// Column (language-direction) stats over pre-mask scores:
// grid (4 qg, 64 bh); block reduces 1024 q rows -> spm [4][64][256][2] (m,l).
// ---------------------------------------------------------------------------
__global__ __launch_bounds__(256) void col_stats(
    const bf16* __restrict__ q, const bf16* __restrict__ kk,
    float* __restrict__ spm) {
  __shared__ short k_lds[256 * 72];
  __shared__ float wm[4][256];
  __shared__ float wl[4][256];
  const int tid = threadIdx.x, wave = tid >> 6, lane = tid & 63;
  const int qg = blockIdx.x, bh = blockIdx.y;
  const int b = bh >> 4, h = bh & 15;
  const size_t krow0 = (size_t)b * NLTOK;
  const int rl = lane & 15, lg = lane >> 4;

#pragma unroll
  for (int it = 0; it < 8; it++) {
    int vv = it * 256 + tid;
    int nl = vv >> 3, c = vv & 7;
    *(bf16x8*)&k_lds[nl * 72 + c * 8] =
        *(const bf16x8*)((const short*)kk + (krow0 + nl) * EMBED + h * HD + c * 8);
  }
  __syncthreads();

  float cm[16], cl[16];
#pragma unroll
  for (int ct = 0; ct < 16; ct++) { cm[ct] = -1e30f; cl[ct] = 0.f; }

  for (int qt = 0; qt < 16; qt++) {
    const short* qrow = (const short*)q +
        ((size_t)b * NVTOK + qg * 1024 + qt * 64 + wave * 16 + rl) * EMBED + h * HD;
    bf16x8 a0 = *(const bf16x8*)(qrow + lg * 8);
    bf16x8 a1 = *(const bf16x8*)(qrow + 32 + lg * 8);
#pragma unroll
    for (int ct = 0; ct < 16; ct++) {
      bf16x8 b0 = *(const bf16x8*)&k_lds[(ct * 16 + rl) * 72 + lg * 8];
      bf16x8 b1 = *(const bf16x8*)&k_lds[(ct * 16 + rl) * 72 + 32 + lg * 8];
      floatx4 s = (floatx4){0.f, 0.f, 0.f, 0.f};
      s = MFMA(a0, b0, s);
      s = MFMA(a1, b1, s);
      float mt = fmaxf(fmaxf(s[0], s[1]), fmaxf(s[2], s[3]));
      float st = 0.f;
#pragma unroll
      for (int r = 0; r < 4; r++) st += __expf(fminf(s[r] - mt, 0.f));
      float nm = fmaxf(cm[ct], mt);
      cl[ct] = cl[ct] * __expf(fminf(cm[ct] - nm, 0.f)) + st * __expf(fminf(mt - nm, 0.f));
      cm[ct] = nm;
    }
  }
  // merge the 4 row-groups (lg) of each wave
#pragma unroll
  for (int ct = 0; ct < 16; ct++) {
    float om = __shfl_xor(cm[ct], 16), ol = __shfl_xor(cl[ct], 16);
    float nm = fmaxf(cm[ct], om);
    cl[ct] = cl[ct] * __expf(fminf(cm[ct] - nm, 0.f)) + ol * __expf(fminf(om - nm, 0.f));
    cm[ct] = nm;
    om = __shfl_xor(cm[ct], 32); ol = __shfl_xor(cl[ct], 32);
    nm = fmaxf(cm[ct], om);
    cl[ct] = cl[ct] * __expf(fminf(cm[ct] - nm, 0.f)) + ol * __expf(fminf(om - nm, 0.f));
    cm[ct] = nm;
    if (lg == 0) { wm[wave][ct * 16 + rl] = cm[ct]; wl[wave][ct * 16 + rl] = cl[ct]; }
  }
  __syncthreads();
  {
    int col = tid;
    float m = wm[0][col], l = wl[0][col];
#pragma unroll
    for (int w2 = 1; w2 < 4; w2++) {
      float mi = wm[w2][col], li = wl[w2][col];
      float nm = fmaxf(m, mi);
      l = l * __expf(fminf(m - nm, 0.f)) + li * __expf(fminf(mi - nm, 0.f));
      m = nm;
    }
    float* sp = spm + (((size_t)qg * 64 + bh) * 256 + col) * 2;
    sp[0] = m;
    sp[1] = l;
  }
}

// spm [4][64][256][2] -> sfin [64][256][2]
__global__ void stats_merge(const float* __restrict__ spm, float* __restrict__ sf) {
  int bh = blockIdx.x, col = threadIdx.x;
  float m = -1e30f, l = 0.f;
#pragma unroll
  for (int qg = 0; qg < 4; qg++) {
    const float* p = spm + (((size_t)qg * 64 + bh) * 256 + col) * 2;
    float mi = p[0], li = p[1];
    float nm = fmaxf(m, mi);
    l = l * __expf(fminf(m - nm, 0.f)) + li * __expf(fminf(mi - nm, 0.f));
    m = nm;
  }
  float* o = sf + ((size_t)bh * 256 + col) * 2;
  o[0] = m;
  o[1] = fmaxf(l, 1e-20f);
}

// ---------------------------------------------------------------------------
// Vision-direction attention: per block (64 q rows, one bh):
// S = q.k^T (q pre-scaled), masked row softmax, out = P @ val_l.
// ---------------------------------------------------------------------------
__global__ __launch_bounds__(256) void attn_fwd_v(
    const bf16* __restrict__ q,    // [B*NV][E] pre-scaled
    const bf16* __restrict__ kk,   // [B*NL][E]
    const bf16* __restrict__ vlT,  // [B*H][HD][NL]
    const int* __restrict__ mask,  // [B][NL]
    bf16* __restrict__ ovh) {      // [B*NV][E]
  __shared__ short kp_lds[256 * 72];  // k tile (stride 72), then P (stride 264)
  __shared__ float mbias[256];
  const int tid = threadIdx.x, wave = tid >> 6, lane = tid & 63;
  const int qt = blockIdx.x, bh = blockIdx.y;
  const int b = bh >> 4, h = bh & 15;
  const size_t qrow0 = (size_t)b * NVTOK + qt * 64;
  const size_t krow0 = (size_t)b * NLTOK;
  const int rl = lane & 15, lg = lane >> 4;

#pragma unroll
  for (int it = 0; it < 8; it++) {
    int vv = it * 256 + tid;
    int nl = vv >> 3, c = vv & 7;
    *(bf16x8*)&kp_lds[nl * 72 + c * 8] =
        *(const bf16x8*)((const short*)kk + (krow0 + nl) * EMBED + h * HD + c * 8);
  }
  mbias[tid] = mask[b * NLTOK + tid] ? 0.0f : -1e9f;
  __syncthreads();

  floatx4 sacc[16];
#pragma unroll
  for (int ct = 0; ct < 16; ct++) sacc[ct] = (floatx4){0.f, 0.f, 0.f, 0.f};
  const short* qrow = (const short*)q + (qrow0 + wave * 16 + rl) * EMBED + h * HD;
  bf16x8 a0 = *(const bf16x8*)(qrow + lg * 8);
  bf16x8 a1 = *(const bf16x8*)(qrow + 32 + lg * 8);
#pragma unroll
  for (int ct = 0; ct < 16; ct++) {
    bf16x8 b0 = *(const bf16x8*)&kp_lds[(ct * 16 + rl) * 72 + lg * 8];
    bf16x8 b1 = *(const bf16x8*)&kp_lds[(ct * 16 + rl) * 72 + 32 + lg * 8];
    sacc[ct] = MFMA(a0, b0, sacc[ct]);
    sacc[ct] = MFMA(a1, b1, sacc[ct]);
  }
  __syncthreads();  // all waves done reading k

  // masked row softmax (rows = wave*16 + lg*4 + r, cols = ct*16 + rl)
  float rmax[4] = {-1e30f, -1e30f, -1e30f, -1e30f};
#pragma unroll
  for (int ct = 0; ct < 16; ct++) {
    float mb = mbias[ct * 16 + rl];
#pragma unroll
    for (int r = 0; r < 4; r++) {
      sacc[ct][r] += mb;
      rmax[r] = fmaxf(rmax[r], sacc[ct][r]);
    }
  }
#pragma unroll
  for (int r = 0; r < 4; r++) {
    rmax[r] = fmaxf(rmax[r], __shfl_xor(rmax[r], 1));
    rmax[r] = fmaxf(rmax[r], __shfl_xor(rmax[r], 2));
    rmax[r] = fmaxf(rmax[r], __shfl_xor(rmax[r], 4));
    rmax[r] = fmaxf(rmax[r], __shfl_xor(rmax[r], 8));
  }
  float rsum[4] = {0.f, 0.f, 0.f, 0.f};
#pragma unroll
  for (int ct = 0; ct < 16; ct++)
#pragma unroll
    for (int r = 0; r < 4; r++) {
      sacc[ct][r] = __expf(fminf(sacc[ct][r] - rmax[r], 0.f));
      rsum[r] += sacc[ct][r];
    }
#pragma unroll
  for (int r = 0; r < 4; r++) {
    rsum[r] += __shfl_xor(rsum[r], 1);
    rsum[r] += __shfl_xor(rsum[r], 2);
    rsum[r] += __shfl_xor(rsum[r], 4);
    rsum[r] += __shfl_xor(rsum[r], 8);
    rsum[r] = 1.0f / fmaxf(rsum[r], 1e-20f);
  }
  // write P (bf16) into kp_lds, stride 264, rows = q-local, cols = nl
#pragma unroll
  for (int ct = 0; ct < 16; ct++)
#pragma unroll
    for (int r = 0; r < 4; r++)
      kp_lds[(wave * 16 + lg * 4 + r) * 264 + ct * 16 + rl] = f2bs(sacc[ct][r] * rsum[r]);
  __syncthreads();

  // PV: out rows wave*16..+16, 64 cols; vlT [bh][d][nl]
  const short* vbase = (const short*)vlT + (size_t)bh * 64 * 256;
  floatx4 oacc[4];
#pragma unroll
  for (int dt = 0; dt < 4; dt++) oacc[dt] = (floatx4){0.f, 0.f, 0.f, 0.f};
#pragma unroll
  for (int ks = 0; ks < 8; ks++) {
    bf16x8 af = *(const bf16x8*)&kp_lds[(wave * 16 + rl) * 264 + ks * 32 + lg * 8];
#pragma unroll
    for (int dt = 0; dt < 4; dt++) {
      bf16x8 bfr = *(const bf16x8*)(vbase + (size_t)(dt * 16 + rl) * 256 + ks * 32 + lg * 8);
      oacc[dt] = MFMA(af, bfr, oacc[dt]);
    }
  }
#pragma unroll
  for (int dt = 0; dt < 4; dt++)
#pragma unroll
    for (int r = 0; r < 4; r++) {
      size_t row = qrow0 + wave * 16 + lg * 4 + r;
      ((short*)ovh)[row * EMBED + h * HD + dt * 16 + rl] = f2bs(oacc[dt][r]);
    }
}

__global__ void zero_f32(float* __restrict__ p, int n) {
  int i = blockIdx.x * 256 + threadIdx.x;
  if (i < n) p[i] = 0.f;
}

// ---------------------------------------------------------------------------
// Language-direction attention: per block (512 q rows, one bh):
// recompute S, P_l = exp(S - m_col)/l_col, atomically accumulate
// P_l^T @ val_v into olacc [B*NL][E] fp32.
// ---------------------------------------------------------------------------
__global__ __launch_bounds__(256) void attn_fwd_l(
    const bf16* __restrict__ q,   // [B*NV][E] pre-scaled
    const bf16* __restrict__ kk,  // [B*NL][E]
    const bf16* __restrict__ vv,  // [B*NV][E] val_v
    const float* __restrict__ sf, // [64 bh][256][2]
    float* __restrict__ olacc) {  // [B*NL][E] fp32, pre-zeroed
  __shared__ short k_lds[256 * 72];
  __shared__ short PT[256 * 40];
  __shared__ short vvT[64 * 40];
  __shared__ float sm[256];
  __shared__ float sl[256];
  const int tid = threadIdx.x, wave = tid >> 6, lane = tid & 63;
  const int chunk = blockIdx.x, bh = blockIdx.y;
  const int b = bh >> 4, h = bh & 15;
  const size_t krow0 = (size_t)b * NLTOK;
  const size_t qbase = (size_t)b * NVTOK + chunk * 512;
  const int rl = lane & 15, lg = lane >> 4;

#pragma unroll
  for (int it = 0; it < 8; it++) {
    int vvi = it * 256 + tid;
    int nl = vvi >> 3, c = vvi & 7;
    *(bf16x8*)&k_lds[nl * 72 + c * 8] =
        *(const bf16x8*)((const short*)kk + (krow0 + nl) * EMBED + h * HD + c * 8);
  }
  sm[tid] = sf[((size_t)bh * 256 + tid) * 2];
  sl[tid] = 1.0f / sf[((size_t)bh * 256 + tid) * 2 + 1];
  __syncthreads();

  floatx4 acc[4][4];
#pragma unroll
  for (int rt = 0; rt < 4; rt++)
#pragma unroll
    for (int dt = 0; dt < 4; dt++) acc[rt][dt] = (floatx4){0.f, 0.f, 0.f, 0.f};

  const int qrt = wave & 1, ctb = (wave >> 1) * 8;
  for (int qs = 0; qs < 16; qs++) {
    const short* qrow = (const short*)q + (qbase + qs * 32 + qrt * 16 + rl) * EMBED + h * HD;
    bf16x8 a0 = *(const bf16x8*)(qrow + lg * 8);
    bf16x8 a1 = *(const bf16x8*)(qrow + 32 + lg * 8);
    floatx4 s8[8];
#pragma unroll
    for (int i = 0; i < 8; i++) {
      int ct = ctb + i;
      bf16x8 b0 = *(const bf16x8*)&k_lds[(ct * 16 + rl) * 72 + lg * 8];
      bf16x8 b1 = *(const bf16x8*)&k_lds[(ct * 16 + rl) * 72 + 32 + lg * 8];
      floatx4 s = (floatx4){0.f, 0.f, 0.f, 0.f};
      s = MFMA(a0, b0, s);
      s = MFMA(a1, b1, s);
      s8[i] = s;
    }
    __syncthreads();  // previous iteration's PT/vvT reads complete
#pragma unroll
    for (int i = 0; i < 8; i++) {
      int col = (ctb + i) * 16 + rl;
      float m = sm[col], linv = sl[col];
#pragma unroll
      for (int r = 0; r < 4; r++)
        PT[col * 40 + qrt * 16 + lg * 4 + r] = f2bs(__expf(fminf(s8[i][r] - m, 0.f)) * linv);
    }
    {
      int qq = tid >> 3, c = tid & 7;
      bf16x8 vvv = *(const bf16x8*)((const short*)vv + (qbase + qs * 32 + qq) * EMBED + h * HD + c * 8);
      const short* vp = (const short*)&vvv;
#pragma unroll
      for (int j = 0; j < 8; j++) vvT[(c * 8 + j) * 40 + qq] = vp[j];
    }
    __syncthreads();
#pragma unroll
    for (int rt = 0; rt < 4; rt++) {
      bf16x8 af = *(const bf16x8*)&PT[(wave * 64 + rt * 16 + rl) * 40 + lg * 8];
#pragma unroll
      for (int dt = 0; dt < 4; dt++) {
        bf16x8 bfr = *(const bf16x8*)&vvT[(dt * 16 + rl) * 40 + lg * 8];
        acc[rt][dt] = MFMA(af, bfr, acc[rt][dt]);
      }
    }
  }
#pragma unroll
  for (int rt = 0; rt < 4; rt++)
#pragma unroll
    for (int dt = 0; dt < 4; dt++)
#pragma unroll
      for (int r = 0; r < 4; r++) {
        int nl = wave * 64 + rt * 16 + lg * 4 + r;
        int d = dt * 16 + rl;
        atomicAdd(&olacc[((size_t)b * NLTOK + nl) * EMBED + h * HD + d], acc[rt][dt][r]);
      }
}

__global__ void finalize_out_l(const float* __restrict__ olacc, bf16* __restrict__ olh) {
  int i = blockIdx.x * 256 + threadIdx.x;
  if (i < 1024 * 1024) olh[i] = __float2bfloat16(olacc[i]);
}

// ---------------------------------------------------------------------------
extern "C" void kernel_launch(void* const* d_in, const int* in_sizes, int n_in,
                              void* d_out, int out_size, void* d_ws, size_t ws_size,
                              hipStream_t stream) {
  (void)in_sizes; (void)n_in; (void)out_size; (void)ws_size;
  const void* v_raw    = d_in[0];
  const void* l_raw    = d_in[1];
  const int*  mask     = (const int*)d_in[2];
  const void* W_v2q = d_in[3];  const void* b_v2q = d_in[4];
  const void* W_l2k = d_in[5];  const void* b_l2k = d_in[6];
  const void* W_v2v = d_in[7];  const void* b_v2v = d_in[8];
  const void* W_l2v = d_in[9];  const void* b_l2v = d_in[10];
  const void* W_v2o = d_in[11]; const void* b_v2o = d_in[12];
  const void* W_l2o = d_in[13]; const void* b_l2o = d_in[14];

  char* ws = (char*)d_ws;
  size_t off = 0;
  auto alloc = [&](size_t bytes) -> void* {
    void* p = ws + off;
    off += (bytes + 255) & ~(size_t)255;
    return p;
  };
  int*  flag   = (int*)alloc(256);
  bf16* vb     = (bf16*)alloc((size_t)16777216 * 2);
  bf16* lb     = (bf16*)alloc((size_t)786432 * 2);
  bf16* bq     = (bf16*)alloc(2048);
  bf16* bk     = (bf16*)alloc(2048);
  bf16* bvv    = (bf16*)alloc(2048);
  bf16* bvl    = (bf16*)alloc(2048);
  bf16* bov    = (bf16*)alloc(2048);
  bf16* bol    = (bf16*)alloc(1536);
  bf16* Wt_v2q = (bf16*)alloc((size_t)1024 * 1024 * 2);
  bf16* Wt_l2k = (bf16*)alloc((size_t)1024 * 768 * 2);
  bf16* Wt_v2v = (bf16*)alloc((size_t)1024 * 1024 * 2);
  bf16* Wt_l2v = (bf16*)alloc((size_t)1024 * 768 * 2);
  bf16* Wt_v2o = (bf16*)alloc((size_t)1024 * 1024 * 2);
  bf16* Wt_l2o = (bf16*)alloc((size_t)768 * 1024 * 2);
  bf16* qb     = (bf16*)alloc((size_t)16384 * 1024 * 2);
  bf16* kb     = (bf16*)alloc((size_t)1024 * 1024 * 2);
  bf16* vvb    = (bf16*)alloc((size_t)16384 * 1024 * 2);
  bf16* vlb    = (bf16*)alloc((size_t)1024 * 1024 * 2);
  bf16* vlT    = (bf16*)alloc((size_t)64 * 64 * 256 * 2);
  bf16* ovh    = (bf16*)alloc((size_t)16384 * 1024 * 2);
  float* spm   = (float*)alloc((size_t)4 * 64 * 256 * 2 * 4);
  float* sfin  = (float*)alloc((size_t)64 * 256 * 2 * 4);
  float* olacc = (float*)alloc((size_t)1024 * 1024 * 4);
  bf16* olh    = (bf16*)alloc((size_t)1024 * 1024 * 2);

  detect_dtype<<<1, 256, 0, stream>>>((const unsigned*)v_raw, flag);

  convert_to_bf16<<<65536, 256, 0, stream>>>(v_raw, vb, 16777216, flag);
  convert_to_bf16<<<3072, 256, 0, stream>>>(l_raw, lb, 786432, flag);
  convert_to_bf16<<<4, 256, 0, stream>>>(b_v2q, bq, 1024, flag);
  convert_to_bf16<<<4, 256, 0, stream>>>(b_l2k, bk, 1024, flag);
  convert_to_bf16<<<4, 256, 0, stream>>>(b_v2v, bvv, 1024, flag);
  convert_to_bf16<<<4, 256, 0, stream>>>(b_l2v, bvl, 1024, flag);
  convert_to_bf16<<<4, 256, 0, stream>>>(b_v2o, bov, 1024, flag);
  convert_to_bf16<<<3, 256, 0, stream>>>(b_l2o, bol, 768, flag);
  convert_transpose<<<4096, 256, 0, stream>>>(W_v2q, Wt_v2q, 1024, 1024, flag);
  convert_transpose<<<3072, 256, 0, stream>>>(W_l2k, Wt_l2k, 768, 1024, flag);
  convert_transpose<<<4096, 256, 0, stream>>>(W_v2v, Wt_v2v, 1024, 1024, flag);
  convert_transpose<<<3072, 256, 0, stream>>>(W_l2v, Wt_l2v, 768, 1024, flag);
  convert_transpose<<<4096, 256, 0, stream>>>(W_v2o, Wt_v2o, 1024, 1024, flag);
  convert_transpose<<<3072, 256, 0, stream>>>(W_l2o, Wt_l2o, 1024, 768, flag);

  const int* bf16out = flag + 1;  // constant 0
  // projections (scale folded into q)
  gemm_nt<<<dim3(128, 8), 256, 0, stream>>>(vb, Wt_v2q, bq, qb, 0, 16384, 1024, 1024, QSCALE, bf16out);
  gemm_nt<<<dim3(8, 8), 256, 0, stream>>>(lb, Wt_l2k, bk, kb, 0, 1024, 1024, 768, 1.0f, bf16out);
  gemm_nt<<<dim3(128, 8), 256, 0, stream>>>(vb, Wt_v2v, bvv, vvb, 0, 16384, 1024, 1024, 1.0f, bf16out);
  gemm_nt<<<dim3(8, 8), 256, 0, stream>>>(lb, Wt_l2v, bvl, vlb, 0, 1024, 1024, 768, 1.0f, bf16out);
  transpose_vl_heads<<<4096, 256, 0, stream>>>(vlb, vlT);

  // attention
  col_stats<<<dim3(4, 64), 256, 0, stream>>>(qb, kb, spm);
  stats_merge<<<64, 256, 0, stream>>>(spm, sfin);
  attn_fwd_v<<<dim3(64, 64), 256, 0, stream>>>(qb, kb, vlT, mask, ovh);
  zero_f32<<<4096, 256, 0, stream>>>(olacc, 1024 * 1024);
  attn_fwd_l<<<dim3(8, 64), 256, 0, stream>>>(qb, kb, vvb, sfin, olacc);
  finalize_out_l<<<4096, 256, 0, stream>>>(olacc, olh);

  // output projections straight into d_out (dtype per flag)
  gemm_nt<<<dim3(128, 8), 256, 0, stream>>>(ovh, Wt_v2o, bov, d_out, 0, 16384, 1024, 1024, 1.0f, flag);
  gemm_nt<<<dim3(8, 6), 256, 0, stream>>>(olh, Wt_l2o, bol, d_out, 16777216LL, 1024, 768, 1024, 1.0f, flag);
}

// Round 3
// 644.776 us; speedup vs baseline: 1.0811x; 1.0811x over previous
//
#include <hip/hip_runtime.h>
#include <hip/hip_bf16.h>

#define EMBED 1024
#define HEADS 16
#define HD 64
#define NVTOK 4096
#define NLTOK 256
#define BATCH 4
#define QSCALE 0.25f   // HEADS**-0.5

typedef __hip_bfloat16 bf16;
typedef __attribute__((ext_vector_type(8))) short bf16x8;
typedef __attribute__((ext_vector_type(4))) float floatx4;

#define MFMA(a, b, c) __builtin_amdgcn_mfma_f32_16x16x32_bf16((a), (b), (c), 0, 0, 0)

static __device__ __forceinline__ short f2bs(float x) {
  bf16 h = __float2bfloat16(x);
  return *reinterpret_cast<short*>(&h);
}
static __device__ __forceinline__ float b2f(bf16 x) { return __bfloat162float(x); }

// Async global->LDS, 16B per lane. LDS dest = wave-uniform base + lane*16.
typedef const __attribute__((address_space(1))) char ga_char;
typedef __attribute__((address_space(3))) char ls_char;
static __device__ __forceinline__ void load_lds16(const void* g, void* lds) {
  __builtin_amdgcn_global_load_lds((ga_char*)g, (ls_char*)(unsigned)(size_t)(lds), 16, 0, 0);
}

// ---------------------------------------------------------------------------
// Input dtype detector (fp32 vs bf16 packed), see round-2 notes. flag[0]=1 => fp32.
// flag[1] = constant 0 (bf16-output selector for internal GEMMs).
// ---------------------------------------------------------------------------
__global__ void detect_dtype(const unsigned* __restrict__ v, int* __restrict__ flag) {
  __shared__ int cnt;
  if (threadIdx.x == 0) cnt = 0;
  __syncthreads();
  unsigned u = v[threadIdx.x];
  int mid = (int)((u >> 7) & 0xFF);
  if (mid >= 110 && mid <= 140) atomicAdd(&cnt, 1);
  __syncthreads();
  if (threadIdx.x == 0) {
    flag[0] = (cnt < 192) ? 1 : 0;
    flag[1] = 0;
  }
}

// ---------------------------------------------------------------------------
// Vectorized input convert (4 elements/thread). n4 = n/4.
// ---------------------------------------------------------------------------
__global__ void convert_to_bf16_v4(const void* __restrict__ src, bf16* __restrict__ dst,
                                   int n4, const int* __restrict__ flag) {
  int i = blockIdx.x * 256 + threadIdx.x;
  if (i >= n4) return;
  short4 o;
  if (flag[0]) {
    float4 f = ((const float4*)src)[i];
    o.x = f2bs(f.x); o.y = f2bs(f.y); o.z = f2bs(f.z); o.w = f2bs(f.w);
  } else {
    o = ((const short4*)src)[i];
  }
  ((short4*)dst)[i] = o;
}

// Batched weight convert+transpose: src [R][C] -> dst [C][R] bf16, 6 weights.
struct WTArgs {
  const void* src[6];
  bf16* dst[6];
  int R[6];
  int C[6];
};
__global__ void convert_transpose_all(WTArgs a, const int* __restrict__ flag) {
  int z = blockIdx.y;
  int idx = blockIdx.x * 256 + threadIdx.x;
  int R = a.R[z], C = a.C[z];
  if (idx >= R * C) return;
  int r = idx / C, c = idx - r * C;
  float x = flag[0] ? ((const float*)a.src[z])[idx] : b2f(((const bf16*)a.src[z])[idx]);
  a.dst[z][c * R + r] = __float2bfloat16(x);
}

// Batched bias convert.
struct BArgs {
  const void* src[6];
  bf16* dst[6];
  int n[6];
};
__global__ void convert_bias_all(BArgs a, const int* __restrict__ flag) {
  int z = blockIdx.y;
  int i = blockIdx.x * 256 + threadIdx.x;
  if (i >= a.n[z]) return;
  float x = flag[0] ? ((const float*)a.src[z])[i] : b2f(((const bf16*)a.src[z])[i]);
  a.dst[z][i] = __float2bfloat16(x);
}

// ---------------------------------------------------------------------------
// val_l per-head transpose: vl [B*NL][E] -> vlT [B*H][HD][NL]
// ---------------------------------------------------------------------------
__global__ void transpose_vl_heads(const bf16* __restrict__ vl, bf16* __restrict__ vlT) {
  int idx = blockIdx.x * 256 + threadIdx.x;  // 64bh * 64d * 256nl
  if (idx >= 64 * 64 * 256) return;
  int nl = idx & 255;
  int d  = (idx >> 8) & 63;
  int bh = idx >> 14;
  int b = bh >> 4, h = bh & 15;
  vlT[idx] = vl[((size_t)b * NLTOK + nl) * EMBED + h * HD + d];
}

// ---------------------------------------------------------------------------
// NT GEMM with global_load_lds staging (m97 pattern):
// C[M][N] = (A[M][K] @ Bt[N][K]^T + bias) * alpha, bf16 in.
// Output: bf16 (outf[0]==0) or fp32 (outf[0]==1), at element offset coff.
// 128x128 tile, BK=32, unpadded LDS [128][32] shorts (8 KB each).
// ---------------------------------------------------------------------------
__global__ __launch_bounds__(256) void gemm_nt(
    const bf16* __restrict__ A, const bf16* __restrict__ Bt,
    const bf16* __restrict__ bias, void* __restrict__ Cout, long long coff,
    int M, int N, int K, float alpha, const int* __restrict__ outf) {
  __shared__ short As[4096];
  __shared__ short Bs[4096];
  const int f32o = outf[0];
  const int tid = threadIdx.x;
  const int wave = tid >> 6, lane = tid & 63;
  const int bm = blockIdx.x * 128, bn = blockIdx.y * 128;
  const int wr = (wave & 1) * 64, wc = (wave >> 1) * 64;
  const int rl = lane & 15, kg = (lane >> 4) * 8;

  // Staging geometry: per call-site a wave writes 64 lanes x 16B = 1 KB.
  // Site covers 64 rows (4 waves x 16 rows); lane -> row wave*16+(lane>>2),
  // k-chunk (lane&3)*8. Two sites per matrix (rows 0..63, 64..127).
  const int srow = wave * 16 + (lane >> 2);
  const int scol = (lane & 3) * 8;
  const short* Ag = (const short*)A + (size_t)(bm + srow) * K + scol;
  const short* Bg = (const short*)Bt + (size_t)(bn + srow) * K + scol;
  short* As0 = &As[wave * 512];
  short* As1 = &As[2048 + wave * 512];
  short* Bs0 = &Bs[wave * 512];
  short* Bs1 = &Bs[2048 + wave * 512];
  const size_t rstep = (size_t)64 * K;

  floatx4 acc[4][4];
#pragma unroll
  for (int i = 0; i < 4; i++)
#pragma unroll
    for (int j = 0; j < 4; j++) acc[i][j] = (floatx4){0.f, 0.f, 0.f, 0.f};

  for (int k0 = 0; k0 < K; k0 += 32) {
    __syncthreads();
    load_lds16(Ag + k0, As0);
    load_lds16(Ag + rstep + k0, As1);
    load_lds16(Bg + k0, Bs0);
    load_lds16(Bg + rstep + k0, Bs1);
    __syncthreads();
    bf16x8 af[4], bfr[4];
#pragma unroll
    for (int i = 0; i < 4; i++) af[i]  = *(const bf16x8*)&As[(wr + i * 16 + rl) * 32 + kg];
#pragma unroll
    for (int j = 0; j < 4; j++) bfr[j] = *(const bf16x8*)&Bs[(wc + j * 16 + rl) * 32 + kg];
#pragma unroll
    for (int i = 0; i < 4; i++)
#pragma unroll
      for (int j = 0; j < 4; j++) acc[i][j] = MFMA(af[i], bfr[j], acc[i][j]);
  }

  const int rg = (lane >> 4) * 4;
#pragma unroll
  for (int j = 0; j < 4; j++) {
    int col = bn + wc + j * 16 + rl;
    float bv = b2f(bias[col]);
#pragma unroll
    for (int i = 0; i < 4; i++) {
#pragma unroll
      for (int r = 0; r < 4; r++) {
        int row = bm + wr + i * 16 + rg + r;
        float val = (acc[i][j][r] + bv) * alpha;
        long long idx = coff + (long long)row * N + col;
        if (f32o) ((float*)Cout)[idx] = val;
        else      ((bf16*)Cout)[idx]  = __float2bfloat16(val);
      }
    }
  }
}

// ---------------------------------------------------------------------------
// Vision-direction attention + fused column stats: per block (64 q rows, bh):
// S = q.k^T (q pre-scaled); pre-mask column partials (m,l) -> spart;
// masked row softmax; out = P @ val_l.
// ---------------------------------------------------------------------------
__global__ __launch_bounds__(256) void attn_fwd_v(
    const bf16* __restrict__ q,    // [B*NV][E] pre-scaled
    const bf16* __restrict__ kk,   // [B*NL][E]
    const bf16* __restrict__ vlT,  // [B*H][HD][NL]
    const int* __restrict__ mask,  // [B][NL]
    bf16* __restrict__ ovh,        // [B*NV][E]
    float* __restrict__ spart) {   // [64 qt][64 bh][256][2]
  __shared__ short kp_lds[256 * 72];  // k tile (stride 72), then P (stride 264)
  __shared__ float st_m[4][256];
  __shared__ float st_l[4][256];
  __shared__ float mbias[256];
  const int tid = threadIdx.x, wave = tid >> 6, lane = tid & 63;
  const int qt = blockIdx.x, bh = blockIdx.y;
  const int b = bh >> 4, h = bh & 15;
  const size_t qrow0 = (size_t)b * NVTOK + qt * 64;
  const size_t krow0 = (size_t)b * NLTOK;
  const int rl = lane & 15, lg = lane >> 4;

#pragma unroll
  for (int it = 0; it < 8; it++) {
    int vv = it * 256 + tid;
    int nl = vv >> 3, c = vv & 7;
    *(bf16x8*)&kp_lds[nl * 72 + c * 8] =
        *(const bf16x8*)((const short*)kk + (krow0 + nl) * EMBED + h * HD + c * 8);
  }
  mbias[tid] = mask[b * NLTOK + tid] ? 0.0f : -1e9f;
  __syncthreads();

  floatx4 sacc[16];
#pragma unroll
  for (int ct = 0; ct < 16; ct++) sacc[ct] = (floatx4){0.f, 0.f, 0.f, 0.f};
  const short* qrow = (const short*)q + (qrow0 + wave * 16 + rl) * EMBED + h * HD;
  bf16x8 a0 = *(const bf16x8*)(qrow + lg * 8);
  bf16x8 a1 = *(const bf16x8*)(qrow + 32 + lg * 8);
#pragma unroll
  for (int ct = 0; ct < 16; ct++) {
    bf16x8 b0 = *(const bf16x8*)&kp_lds[(ct * 16 + rl) * 72 + lg * 8];
    bf16x8 b1 = *(const bf16x8*)&kp_lds[(ct * 16 + rl) * 72 + 32 + lg * 8];
    sacc[ct] = MFMA(a0, b0, sacc[ct]);
    sacc[ct] = MFMA(a1, b1, sacc[ct]);
  }
  __syncthreads();  // all waves done reading k

  // pre-mask column partial stats over this wave's 16 rows
#pragma unroll
  for (int ct = 0; ct < 16; ct++) {
    float m = fmaxf(fmaxf(sacc[ct][0], sacc[ct][1]), fmaxf(sacc[ct][2], sacc[ct][3]));
    m = fmaxf(m, __shfl_xor(m, 16));
    m = fmaxf(m, __shfl_xor(m, 32));
    float s = 0.f;
#pragma unroll
    for (int r = 0; r < 4; r++) s += __expf(fminf(sacc[ct][r] - m, 0.f));
    s += __shfl_xor(s, 16);
    s += __shfl_xor(s, 32);
    if (lg == 0) { st_m[wave][ct * 16 + rl] = m; st_l[wave][ct * 16 + rl] = s; }
  }

  // masked row softmax (rows = wave*16 + lg*4 + r, cols = ct*16 + rl)
  float rmax[4] = {-1e30f, -1e30f, -1e30f, -1e30f};
#pragma unroll
  for (int ct = 0; ct < 16; ct++) {
    float mb = mbias[ct * 16 + rl];
#pragma unroll
    for (int r = 0; r < 4; r++) {
      sacc[ct][r] += mb;
      rmax[r] = fmaxf(rmax[r], sacc[ct][r]);
    }
  }
#pragma unroll
  for (int r = 0; r < 4; r++) {
    rmax[r] = fmaxf(rmax[r], __shfl_xor(rmax[r], 1));
    rmax[r] = fmaxf(rmax[r], __shfl_xor(rmax[r], 2));
    rmax[r] = fmaxf(rmax[r], __shfl_xor(rmax[r], 4));
    rmax[r] = fmaxf(rmax[r], __shfl_xor(rmax[r], 8));
  }
  float rsum[4] = {0.f, 0.f, 0.f, 0.f};
#pragma unroll
  for (int ct = 0; ct < 16; ct++)
#pragma unroll
    for (int r = 0; r < 4; r++) {
      sacc[ct][r] = __expf(fminf(sacc[ct][r] - rmax[r], 0.f));
      rsum[r] += sacc[ct][r];
    }
#pragma unroll
  for (int r = 0; r < 4; r++) {
    rsum[r] += __shfl_xor(rsum[r], 1);
    rsum[r] += __shfl_xor(rsum[r], 2);
    rsum[r] += __shfl_xor(rsum[r], 4);
    rsum[r] += __shfl_xor(rsum[r], 8);
    rsum[r] = 1.0f / fmaxf(rsum[r], 1e-20f);
  }
  // write P (bf16) into kp_lds, stride 264, rows = q-local, cols = nl
#pragma unroll
  for (int ct = 0; ct < 16; ct++)
#pragma unroll
    for (int r = 0; r < 4; r++)
      kp_lds[(wave * 16 + lg * 4 + r) * 264 + ct * 16 + rl] = f2bs(sacc[ct][r] * rsum[r]);
  __syncthreads();

  // merge 4 waves' column partials -> global spart
  {
    int col = tid;
    float m = st_m[0][col], l = st_l[0][col];
#pragma unroll
    for (int w2 = 1; w2 < 4; w2++) {
      float mi = st_m[w2][col], li = st_l[w2][col];
      float nm = fmaxf(m, mi);
      l = l * __expf(fminf(m - nm, 0.f)) + li * __expf(fminf(mi - nm, 0.f));
      m = nm;
    }
    float* sp = spart + (((size_t)qt * 64 + bh) * 256 + col) * 2;
    sp[0] = m;
    sp[1] = l;
  }

  // PV: out rows wave*16..+16, 64 cols; vlT [bh][d][nl]
  const short* vbase = (const short*)vlT + (size_t)bh * 64 * 256;
  floatx4 oacc[4];
#pragma unroll
  for (int dt = 0; dt < 4; dt++) oacc[dt] = (floatx4){0.f, 0.f, 0.f, 0.f};
#pragma unroll
  for (int ks = 0; ks < 8; ks++) {
    bf16x8 af = *(const bf16x8*)&kp_lds[(wave * 16 + rl) * 264 + ks * 32 + lg * 8];
#pragma unroll
    for (int dt = 0; dt < 4; dt++) {
      bf16x8 bfr = *(const bf16x8*)(vbase + (size_t)(dt * 16 + rl) * 256 + ks * 32 + lg * 8);
      oacc[dt] = MFMA(af, bfr, oacc[dt]);
    }
  }
#pragma unroll
  for (int dt = 0; dt < 4; dt++)
#pragma unroll
    for (int r = 0; r < 4; r++) {
      size_t row = qrow0 + wave * 16 + lg * 4 + r;
      ((short*)ovh)[row * EMBED + h * HD + dt * 16 + rl] = f2bs(oacc[dt][r]);
    }
}

// spart [64 qt][64 bh][256][2] -> sfin [64 bh][256][2]
__global__ void stats_reduce(const float* __restrict__ sp, float* __restrict__ sf) {
  int bh = blockIdx.x, col = threadIdx.x;
  float m = -1e30f, l = 0.f;
  for (int qt = 0; qt < 64; qt++) {
    const float* p = sp + (((size_t)qt * 64 + bh) * 256 + col) * 2;
    float mi = p[0], li = p[1];
    float nm = fmaxf(m, mi);
    l = l * __expf(fminf(m - nm, 0.f)) + li * __expf(fminf(mi - nm, 0.f));
    m = nm;
  }
  float* o = sf + ((size_t)bh * 256 + col) * 2;
  o[0] = m;
  o[1] = fmaxf(l, 1e-20f);
}

__global__ void zero_f32(float* __restrict__ p, int n) {
  int i = blockIdx.x * 256 + threadIdx.x;
  if (i < n) p[i] = 0.f;
}

// ---------------------------------------------------------------------------
// Language-direction attention: per block (512 q rows, one bh):
// recompute S, P_l = exp(S - m_col)/l_col, atomically accumulate
// P_l^T @ val_v into olacc [B*NL][E] fp32.
// ---------------------------------------------------------------------------
__global__ __launch_bounds__(256) void attn_fwd_l(
    const bf16* __restrict__ q,   // [B*NV][E] pre-scaled
    const bf16* __restrict__ kk,  // [B*NL][E]
    const bf16* __restrict__ vv,  // [B*NV][E] val_v
    const float* __restrict__ sf, // [64 bh][256][2]
    float* __restrict__ olacc) {  // [B*NL][E] fp32, pre-zeroed
  __shared__ short k_lds[256 * 72];
  __shared__ short PT[256 * 40];
  __shared__ short vvT[64 * 40];
  __shared__ float sm[256];
  __shared__ float sl[256];
  const int tid = threadIdx.x, wave = tid >> 6, lane = tid & 63;
  const int chunk = blockIdx.x, bh = blockIdx.y;
  const int b = bh >> 4, h = bh & 15;
  const size_t krow0 = (size_t)b * NLTOK;
  const size_t qbase = (size_t)b * NVTOK + chunk * 512;
  const int rl = lane & 15, lg = lane >> 4;

#pragma unroll
  for (int it = 0; it < 8; it++) {
    int vvi = it * 256 + tid;
    int nl = vvi >> 3, c = vvi & 7;
    *(bf16x8*)&k_lds[nl * 72 + c * 8] =
        *(const bf16x8*)((const short*)kk + (krow0 + nl) * EMBED + h * HD + c * 8);
  }
  sm[tid] = sf[((size_t)bh * 256 + tid) * 2];
  sl[tid] = 1.0f / sf[((size_t)bh * 256 + tid) * 2 + 1];
  __syncthreads();

  floatx4 acc[4][4];
#pragma unroll
  for (int rt = 0; rt < 4; rt++)
#pragma unroll
    for (int dt = 0; dt < 4; dt++) acc[rt][dt] = (floatx4){0.f, 0.f, 0.f, 0.f};

  const int qrt = wave & 1, ctb = (wave >> 1) * 8;
  for (int qs = 0; qs < 16; qs++) {
    const short* qrow = (const short*)q + (qbase + qs * 32 + qrt * 16 + rl) * EMBED + h * HD;
    bf16x8 a0 = *(const bf16x8*)(qrow + lg * 8);
    bf16x8 a1 = *(const bf16x8*)(qrow + 32 + lg * 8);
    floatx4 s8[8];
#pragma unroll
    for (int i = 0; i < 8; i++) {
      int ct = ctb + i;
      bf16x8 b0 = *(const bf16x8*)&k_lds[(ct * 16 + rl) * 72 + lg * 8];
      bf16x8 b1 = *(const bf16x8*)&k_lds[(ct * 16 + rl) * 72 + 32 + lg * 8];
      floatx4 s = (floatx4){0.f, 0.f, 0.f, 0.f};
      s = MFMA(a0, b0, s);
      s = MFMA(a1, b1, s);
      s8[i] = s;
    }
    __syncthreads();  // previous iteration's PT/vvT reads complete
#pragma unroll
    for (int i = 0; i < 8; i++) {
      int col = (ctb + i) * 16 + rl;
      float m = sm[col], linv = sl[col];
#pragma unroll
      for (int r = 0; r < 4; r++)
        PT[col * 40 + qrt * 16 + lg * 4 + r] = f2bs(__expf(fminf(s8[i][r] - m, 0.f)) * linv);
    }
    {
      int qq = tid >> 3, c = tid & 7;
      bf16x8 vvv = *(const bf16x8*)((const short*)vv + (qbase + qs * 32 + qq) * EMBED + h * HD + c * 8);
      const short* vp = (const short*)&vvv;
#pragma unroll
      for (int j = 0; j < 8; j++) vvT[(c * 8 + j) * 40 + qq] = vp[j];
    }
    __syncthreads();
#pragma unroll
    for (int rt = 0; rt < 4; rt++) {
      bf16x8 af = *(const bf16x8*)&PT[(wave * 64 + rt * 16 + rl) * 40 + lg * 8];
#pragma unroll
      for (int dt = 0; dt < 4; dt++) {
        bf16x8 bfr = *(const bf16x8*)&vvT[(dt * 16 + rl) * 40 + lg * 8];
        acc[rt][dt] = MFMA(af, bfr, acc[rt][dt]);
      }
    }
  }
#pragma unroll
  for (int rt = 0; rt < 4; rt++)
#pragma unroll
    for (int dt = 0; dt < 4; dt++)
#pragma unroll
      for (int r = 0; r < 4; r++) {
        int nl = wave * 64 + rt * 16 + lg * 4 + r;
        int d = dt * 16 + rl;
        atomicAdd(&olacc[((size_t)b * NLTOK + nl) * EMBED + h * HD + d], acc[rt][dt][r]);
      }
}

__global__ void finalize_out_l(const float* __restrict__ olacc, bf16* __restrict__ olh) {
  int i = blockIdx.x * 256 + threadIdx.x;
  if (i < 1024 * 1024) olh[i] = __float2bfloat16(olacc[i]);
}

// ---------------------------------------------------------------------------
extern "C" void kernel_launch(void* const* d_in, const int* in_sizes, int n_in,
                              void* d_out, int out_size, void* d_ws, size_t ws_size,
                              hipStream_t stream) {
  (void)in_sizes; (void)n_in; (void)out_size; (void)ws_size;
  const void* v_raw = d_in[0];
  const void* l_raw = d_in[1];
  const int*  mask  = (const int*)d_in[2];
  const void* W_v2q = d_in[3];  const void* b_v2q = d_in[4];
  const void* W_l2k = d_in[5];  const void* b_l2k = d_in[6];
  const void* W_v2v = d_in[7];  const void* b_v2v = d_in[8];
  const void* W_l2v = d_in[9];  const void* b_l2v = d_in[10];
  const void* W_v2o = d_in[11]; const void* b_v2o = d_in[12];
  const void* W_l2o = d_in[13]; const void* b_l2o = d_in[14];

  char* ws = (char*)d_ws;
  size_t off = 0;
  auto alloc = [&](size_t bytes) -> void* {
    void* p = ws + off;
    off += (bytes + 255) & ~(size_t)255;
    return p;
  };
  int*  flag   = (int*)alloc(256);
  bf16* vb     = (bf16*)alloc((size_t)16777216 * 2);  // later aliased by ovh
  bf16* lb     = (bf16*)alloc((size_t)786432 * 2);
  bf16* bq     = (bf16*)alloc(2048);
  bf16* bk     = (bf16*)alloc(2048);
  bf16* bvv    = (bf16*)alloc(2048);
  bf16* bvl    = (bf16*)alloc(2048);
  bf16* bov    = (bf16*)alloc(2048);
  bf16* bol    = (bf16*)alloc(1536);
  bf16* Wt_v2q = (bf16*)alloc((size_t)1024 * 1024 * 2);
  bf16* Wt_l2k = (bf16*)alloc((size_t)1024 * 768 * 2);
  bf16* Wt_v2v = (bf16*)alloc((size_t)1024 * 1024 * 2);
  bf16* Wt_l2v = (bf16*)alloc((size_t)1024 * 768 * 2);
  bf16* Wt_v2o = (bf16*)alloc((size_t)1024 * 1024 * 2);
  bf16* Wt_l2o = (bf16*)alloc((size_t)768 * 1024 * 2);
  bf16* qb     = (bf16*)alloc((size_t)16384 * 1024 * 2);
  bf16* kb     = (bf16*)alloc((size_t)1024 * 1024 * 2);
  bf16* vvb    = (bf16*)alloc((size_t)16384 * 1024 * 2);
  bf16* vlb    = (bf16*)alloc((size_t)1024 * 1024 * 2);  // later aliased by olh
  bf16* vlT    = (bf16*)alloc((size_t)64 * 64 * 256 * 2);
  float* spart = (float*)alloc((size_t)64 * 64 * 256 * 2 * 4);  // later aliased by olacc
  float* sfin  = (float*)alloc((size_t)64 * 256 * 2 * 4);
  // aliases (lifetimes verified: vb dead after projections; vlb dead after
  // transpose_vl_heads; spart dead after stats_reduce)
  bf16*  ovh   = vb;
  float* olacc = spart;
  bf16*  olh   = vlb;

  detect_dtype<<<1, 256, 0, stream>>>((const unsigned*)v_raw, flag);

  convert_to_bf16_v4<<<16384, 256, 0, stream>>>(v_raw, vb, 4194304, flag);
  convert_to_bf16_v4<<<768, 256, 0, stream>>>(l_raw, lb, 196608, flag);

  BArgs ba;
  ba.src[0] = b_v2q; ba.dst[0] = bq;  ba.n[0] = 1024;
  ba.src[1] = b_l2k; ba.dst[1] = bk;  ba.n[1] = 1024;
  ba.src[2] = b_v2v; ba.dst[2] = bvv; ba.n[2] = 1024;
  ba.src[3] = b_l2v; ba.dst[3] = bvl; ba.n[3] = 1024;
  ba.src[4] = b_v2o; ba.dst[4] = bov; ba.n[4] = 1024;
  ba.src[5] = b_l2o; ba.dst[5] = bol; ba.n[5] = 768;
  convert_bias_all<<<dim3(4, 6), 256, 0, stream>>>(ba, flag);

  WTArgs wa;
  wa.src[0] = W_v2q; wa.dst[0] = Wt_v2q; wa.R[0] = 1024; wa.C[0] = 1024;
  wa.src[1] = W_l2k; wa.dst[1] = Wt_l2k; wa.R[1] = 768;  wa.C[1] = 1024;
  wa.src[2] = W_v2v; wa.dst[2] = Wt_v2v; wa.R[2] = 1024; wa.C[2] = 1024;
  wa.src[3] = W_l2v; wa.dst[3] = Wt_l2v; wa.R[3] = 768;  wa.C[3] = 1024;
  wa.src[4] = W_v2o; wa.dst[4] = Wt_v2o; wa.R[4] = 1024; wa.C[4] = 1024;
  wa.src[5] = W_l2o; wa.dst[5] = Wt_l2o; wa.R[5] = 1024; wa.C[5] = 768;
  convert_transpose_all<<<dim3(4096, 6), 256, 0, stream>>>(wa, flag);

  const int* bf16out = flag + 1;  // constant 0
  // projections (softmax scale folded into q)
  gemm_nt<<<dim3(128, 8), 256, 0, stream>>>(vb, Wt_v2q, bq, qb, 0, 16384, 1024, 1024, QSCALE, bf16out);
  gemm_nt<<<dim3(8, 8), 256, 0, stream>>>(lb, Wt_l2k, bk, kb, 0, 1024, 1024, 768, 1.0f, bf16out);
  gemm_nt<<<dim3(128, 8), 256, 0, stream>>>(vb, Wt_v2v, bvv, vvb, 0, 16384, 1024, 1024, 1.0f, bf16out);
  gemm_nt<<<dim3(8, 8), 256, 0, stream>>>(lb, Wt_l2v, bvl, vlb, 0, 1024, 1024, 768, 1.0f, bf16out);
  transpose_vl_heads<<<4096, 256, 0, stream>>>(vlb, vlT);

  // attention (vb is dead now; ovh aliases it)
  attn_fwd_v<<<dim3(64, 64), 256, 0, stream>>>(qb, kb, vlT, mask, ovh, spart);
  stats_reduce<<<64, 256, 0, stream>>>(spart, sfin);
  zero_f32<<<4096, 256, 0, stream>>>(olacc, 1024 * 1024);  // spart dead; olacc aliases it
  attn_fwd_l<<<dim3(8, 64), 256, 0, stream>>>(qb, kb, vvb, sfin, olacc);
  finalize_out_l<<<4096, 256, 0, stream>>>(olacc, olh);    // olh aliases vlb (dead)

  // output projections straight into d_out (dtype per flag)
  gemm_nt<<<dim3(128, 8), 256, 0, stream>>>(ovh, Wt_v2o, bov, d_out, 0, 16384, 1024, 1024, 1.0f, flag);
  gemm_nt<<<dim3(8, 6), 256, 0, stream>>>(olh, Wt_l2o, bol, d_out, 16777216LL, 1024, 768, 1024, 1.0f, flag);
}

// Round 4
// 631.690 us; speedup vs baseline: 1.1035x; 1.0207x over previous
//
#include <hip/hip_runtime.h>
#include <hip/hip_bf16.h>

#define EMBED 1024
#define HEADS 16
#define HD 64
#define NVTOK 4096
#define NLTOK 256
#define BATCH 4
#define QSCALE 0.25f   // HEADS**-0.5

typedef __hip_bfloat16 bf16;
typedef __attribute__((ext_vector_type(8))) short bf16x8;
typedef __attribute__((ext_vector_type(4))) float floatx4;

#define MFMA(a, b, c) __builtin_amdgcn_mfma_f32_16x16x32_bf16((a), (b), (c), 0, 0, 0)

static __device__ __forceinline__ short f2bs(float x) {
  bf16 h = __float2bfloat16(x);
  return *reinterpret_cast<short*>(&h);
}
static __device__ __forceinline__ float b2f(bf16 x) { return __bfloat162float(x); }

// Async global->LDS, 16B per lane. LDS dest = wave-uniform base + lane*16.
typedef const __attribute__((address_space(1))) char ga_char;
typedef __attribute__((address_space(3))) char ls_char;
static __device__ __forceinline__ void load_lds16(const void* g, void* lds) {
  __builtin_amdgcn_global_load_lds((ga_char*)g, (ls_char*)(unsigned)(size_t)(lds), 16, 0, 0);
}

// ---------------------------------------------------------------------------
// Input dtype detector (fp32 vs bf16 packed). flag[0]=1 => fp32.
// flag[1] = constant 0 (bf16-output selector for internal GEMMs).
// ---------------------------------------------------------------------------
__global__ void detect_dtype(const unsigned* __restrict__ v, int* __restrict__ flag) {
  __shared__ int cnt;
  if (threadIdx.x == 0) cnt = 0;
  __syncthreads();
  unsigned u = v[threadIdx.x];
  int mid = (int)((u >> 7) & 0xFF);
  if (mid >= 110 && mid <= 140) atomicAdd(&cnt, 1);
  __syncthreads();
  if (threadIdx.x == 0) {
    flag[0] = (cnt < 192) ? 1 : 0;
    flag[1] = 0;
  }
}

// ---------------------------------------------------------------------------
// Vectorized input convert (4 elements/thread). n4 = n/4.
// ---------------------------------------------------------------------------
__global__ void convert_to_bf16_v4(const void* __restrict__ src, bf16* __restrict__ dst,
                                   int n4, const int* __restrict__ flag) {
  int i = blockIdx.x * 256 + threadIdx.x;
  if (i >= n4) return;
  short4 o;
  if (flag[0]) {
    float4 f = ((const float4*)src)[i];
    o.x = f2bs(f.x); o.y = f2bs(f.y); o.z = f2bs(f.z); o.w = f2bs(f.w);
  } else {
    o = ((const short4*)src)[i];
  }
  ((short4*)dst)[i] = o;
}

// Batched weight convert+transpose: src [R][C] -> dst [C][R] bf16, 6 weights.
struct WTArgs {
  const void* src[6];
  bf16* dst[6];
  int R[6];
  int C[6];
};
__global__ void convert_transpose_all(WTArgs a, const int* __restrict__ flag) {
  int z = blockIdx.y;
  int idx = blockIdx.x * 256 + threadIdx.x;
  int R = a.R[z], C = a.C[z];
  if (idx >= R * C) return;
  int r = idx / C, c = idx - r * C;
  float x = flag[0] ? ((const float*)a.src[z])[idx] : b2f(((const bf16*)a.src[z])[idx]);
  a.dst[z][c * R + r] = __float2bfloat16(x);
}

// Batched bias convert.
struct BArgs {
  const void* src[6];
  bf16* dst[6];
  int n[6];
};
__global__ void convert_bias_all(BArgs a, const int* __restrict__ flag) {
  int z = blockIdx.y;
  int i = blockIdx.x * 256 + threadIdx.x;
  if (i >= a.n[z]) return;
  float x = flag[0] ? ((const float*)a.src[z])[i] : b2f(((const bf16*)a.src[z])[i]);
  a.dst[z][i] = __float2bfloat16(x);
}

// ---------------------------------------------------------------------------
// val_l per-head transpose: vl [B*NL][E] -> vlT [B*H][HD][NL]
// ---------------------------------------------------------------------------
__global__ void transpose_vl_heads(const bf16* __restrict__ vl, bf16* __restrict__ vlT) {
  int idx = blockIdx.x * 256 + threadIdx.x;  // 64bh * 64d * 256nl
  if (idx >= 64 * 64 * 256) return;
  int nl = idx & 255;
  int d  = (idx >> 8) & 63;
  int bh = idx >> 14;
  int b = bh >> 4, h = bh & 15;
  vlT[idx] = vl[((size_t)b * NLTOK + nl) * EMBED + h * HD + d];
}

// ---------------------------------------------------------------------------
// NT GEMM with global_load_lds staging (m97 pattern):
// C[M][N] = (A[M][K] @ Bt[N][K]^T + bias) * alpha, bf16 in.
// Output: bf16 (outf[0]==0) or fp32 (outf[0]==1), at element offset coff.
// 128x128 tile, BK=32, unpadded LDS [128][32] shorts (8 KB each).
// ---------------------------------------------------------------------------
__global__ __launch_bounds__(256) void gemm_nt(
    const bf16* __restrict__ A, const bf16* __restrict__ Bt,
    const bf16* __restrict__ bias, void* __restrict__ Cout, long long coff,
    int M, int N, int K, float alpha, const int* __restrict__ outf) {
  __shared__ short As[4096];
  __shared__ short Bs[4096];
  const int f32o = outf[0];
  const int tid = threadIdx.x;
  const int wave = tid >> 6, lane = tid & 63;
  const int bm = blockIdx.x * 128, bn = blockIdx.y * 128;
  const int wr = (wave & 1) * 64, wc = (wave >> 1) * 64;
  const int rl = lane & 15, kg = (lane >> 4) * 8;

  const int srow = wave * 16 + (lane >> 2);
  const int scol = (lane & 3) * 8;
  const short* Ag = (const short*)A + (size_t)(bm + srow) * K + scol;
  const short* Bg = (const short*)Bt + (size_t)(bn + srow) * K + scol;
  short* As0 = &As[wave * 512];
  short* As1 = &As[2048 + wave * 512];
  short* Bs0 = &Bs[wave * 512];
  short* Bs1 = &Bs[2048 + wave * 512];
  const size_t rstep = (size_t)64 * K;

  floatx4 acc[4][4];
#pragma unroll
  for (int i = 0; i < 4; i++)
#pragma unroll
    for (int j = 0; j < 4; j++) acc[i][j] = (floatx4){0.f, 0.f, 0.f, 0.f};

  for (int k0 = 0; k0 < K; k0 += 32) {
    __syncthreads();
    load_lds16(Ag + k0, As0);
    load_lds16(Ag + rstep + k0, As1);
    load_lds16(Bg + k0, Bs0);
    load_lds16(Bg + rstep + k0, Bs1);
    __syncthreads();
    bf16x8 af[4], bfr[4];
#pragma unroll
    for (int i = 0; i < 4; i++) af[i]  = *(const bf16x8*)&As[(wr + i * 16 + rl) * 32 + kg];
#pragma unroll
    for (int j = 0; j < 4; j++) bfr[j] = *(const bf16x8*)&Bs[(wc + j * 16 + rl) * 32 + kg];
#pragma unroll
    for (int i = 0; i < 4; i++)
#pragma unroll
      for (int j = 0; j < 4; j++) acc[i][j] = MFMA(af[i], bfr[j], acc[i][j]);
  }

  const int rg = (lane >> 4) * 4;
#pragma unroll
  for (int j = 0; j < 4; j++) {
    int col = bn + wc + j * 16 + rl;
    float bv = b2f(bias[col]);
#pragma unroll
    for (int i = 0; i < 4; i++) {
#pragma unroll
      for (int r = 0; r < 4; r++) {
        int row = bm + wr + i * 16 + rg + r;
        float val = (acc[i][j][r] + bv) * alpha;
        long long idx = coff + (long long)row * N + col;
        if (f32o) ((float*)Cout)[idx] = val;
        else      ((bf16*)Cout)[idx]  = __float2bfloat16(val);
      }
    }
  }
}

// ---------------------------------------------------------------------------
// Vision-direction attention + fused column stats (LDS-free stats via kp_lds
// reuse): per block (64 q rows, one bh):
//  S = q.k^T (q pre-scaled); pre-mask column partials (m,l) -> spart;
//  masked row softmax; out = P @ val_l.
// LDS = 256*72 shorts + 256 floats = 37888 B -> 4 blocks/CU.
// ---------------------------------------------------------------------------
__global__ __launch_bounds__(256, 4) void attn_fwd_v(
    const bf16* __restrict__ q,    // [B*NV][E] pre-scaled
    const bf16* __restrict__ kk,   // [B*NL][E]
    const bf16* __restrict__ vlT,  // [B*H][HD][NL]
    const int* __restrict__ mask,  // [B][NL]
    bf16* __restrict__ ovh,        // [B*NV][E]
    float* __restrict__ spart) {   // [64 qt][64 bh][256][2]
  __shared__ short kp_lds[256 * 72];  // k tile (stride 72) -> stats scratch -> P (stride 264)
  __shared__ float mbias[256];
  const int tid = threadIdx.x, wave = tid >> 6, lane = tid & 63;
  const int qt = blockIdx.x, bh = blockIdx.y;
  const int b = bh >> 4, h = bh & 15;
  const size_t qrow0 = (size_t)b * NVTOK + qt * 64;
  const size_t krow0 = (size_t)b * NLTOK;
  const int rl = lane & 15, lg = lane >> 4;

#pragma unroll
  for (int it = 0; it < 8; it++) {
    int vv = it * 256 + tid;
    int nl = vv >> 3, c = vv & 7;
    *(bf16x8*)&kp_lds[nl * 72 + c * 8] =
        *(const bf16x8*)((const short*)kk + (krow0 + nl) * EMBED + h * HD + c * 8);
  }
  mbias[tid] = mask[b * NLTOK + tid] ? 0.0f : -1e9f;
  __syncthreads();

  floatx4 sacc[16];
#pragma unroll
  for (int ct = 0; ct < 16; ct++) sacc[ct] = (floatx4){0.f, 0.f, 0.f, 0.f};
  const short* qrow = (const short*)q + (qrow0 + wave * 16 + rl) * EMBED + h * HD;
  bf16x8 a0 = *(const bf16x8*)(qrow + lg * 8);
  bf16x8 a1 = *(const bf16x8*)(qrow + 32 + lg * 8);
#pragma unroll
  for (int ct = 0; ct < 16; ct++) {
    bf16x8 b0 = *(const bf16x8*)&kp_lds[(ct * 16 + rl) * 72 + lg * 8];
    bf16x8 b1 = *(const bf16x8*)&kp_lds[(ct * 16 + rl) * 72 + 32 + lg * 8];
    sacc[ct] = MFMA(a0, b0, sacc[ct]);
    sacc[ct] = MFMA(a1, b1, sacc[ct]);
  }
  __syncthreads();  // all waves done reading k; kp_lds front 8 KB reusable

  // pre-mask column partial stats over this wave's 16 rows, stash in kp_lds
  float* stf = (float*)kp_lds;  // [4 wave][256 col][2]
#pragma unroll
  for (int ct = 0; ct < 16; ct++) {
    float m = fmaxf(fmaxf(sacc[ct][0], sacc[ct][1]), fmaxf(sacc[ct][2], sacc[ct][3]));
    m = fmaxf(m, __shfl_xor(m, 16));
    m = fmaxf(m, __shfl_xor(m, 32));
    float s = 0.f;
#pragma unroll
    for (int r = 0; r < 4; r++) s += __expf(fminf(sacc[ct][r] - m, 0.f));
    s += __shfl_xor(s, 16);
    s += __shfl_xor(s, 32);
    if (lg == 0) {
      stf[wave * 512 + (ct * 16 + rl) * 2]     = m;
      stf[wave * 512 + (ct * 16 + rl) * 2 + 1] = s;
    }
  }
  __syncthreads();
  // merge 4 waves' partials -> global spart
  {
    int col = tid;
    float m = stf[col * 2], l = stf[col * 2 + 1];
#pragma unroll
    for (int w2 = 1; w2 < 4; w2++) {
      float mi = stf[w2 * 512 + col * 2], li = stf[w2 * 512 + col * 2 + 1];
      float nm = fmaxf(m, mi);
      l = l * __expf(fminf(m - nm, 0.f)) + li * __expf(fminf(mi - nm, 0.f));
      m = nm;
    }
    float* sp = spart + (((size_t)qt * 64 + bh) * 256 + col) * 2;
    sp[0] = m;
    sp[1] = l;
  }
  __syncthreads();  // stats scratch consumed; P may overwrite

  // masked row softmax (rows = wave*16 + lg*4 + r, cols = ct*16 + rl)
  float rmax[4] = {-1e30f, -1e30f, -1e30f, -1e30f};
#pragma unroll
  for (int ct = 0; ct < 16; ct++) {
    float mb = mbias[ct * 16 + rl];
#pragma unroll
    for (int r = 0; r < 4; r++) {
      sacc[ct][r] += mb;
      rmax[r] = fmaxf(rmax[r], sacc[ct][r]);
    }
  }
#pragma unroll
  for (int r = 0; r < 4; r++) {
    rmax[r] = fmaxf(rmax[r], __shfl_xor(rmax[r], 1));
    rmax[r] = fmaxf(rmax[r], __shfl_xor(rmax[r], 2));
    rmax[r] = fmaxf(rmax[r], __shfl_xor(rmax[r], 4));
    rmax[r] = fmaxf(rmax[r], __shfl_xor(rmax[r], 8));
  }
  float rsum[4] = {0.f, 0.f, 0.f, 0.f};
#pragma unroll
  for (int ct = 0; ct < 16; ct++)
#pragma unroll
    for (int r = 0; r < 4; r++) {
      sacc[ct][r] = __expf(fminf(sacc[ct][r] - rmax[r], 0.f));
      rsum[r] += sacc[ct][r];
    }
#pragma unroll
  for (int r = 0; r < 4; r++) {
    rsum[r] += __shfl_xor(rsum[r], 1);
    rsum[r] += __shfl_xor(rsum[r], 2);
    rsum[r] += __shfl_xor(rsum[r], 4);
    rsum[r] += __shfl_xor(rsum[r], 8);
    rsum[r] = 1.0f / fmaxf(rsum[r], 1e-20f);
  }
  // write P (bf16) into kp_lds, stride 264, rows = q-local, cols = nl
#pragma unroll
  for (int ct = 0; ct < 16; ct++)
#pragma unroll
    for (int r = 0; r < 4; r++)
      kp_lds[(wave * 16 + lg * 4 + r) * 264 + ct * 16 + rl] = f2bs(sacc[ct][r] * rsum[r]);
  __syncthreads();

  // PV: out rows wave*16..+16, 64 cols; vlT [bh][d][nl]
  const short* vbase = (const short*)vlT + (size_t)bh * 64 * 256;
  floatx4 oacc[4];
#pragma unroll
  for (int dt = 0; dt < 4; dt++) oacc[dt] = (floatx4){0.f, 0.f, 0.f, 0.f};
#pragma unroll
  for (int ks = 0; ks < 8; ks++) {
    bf16x8 af = *(const bf16x8*)&kp_lds[(wave * 16 + rl) * 264 + ks * 32 + lg * 8];
#pragma unroll
    for (int dt = 0; dt < 4; dt++) {
      bf16x8 bfr = *(const bf16x8*)(vbase + (size_t)(dt * 16 + rl) * 256 + ks * 32 + lg * 8);
      oacc[dt] = MFMA(af, bfr, oacc[dt]);
    }
  }
#pragma unroll
  for (int dt = 0; dt < 4; dt++)
#pragma unroll
    for (int r = 0; r < 4; r++) {
      size_t row = qrow0 + wave * 16 + lg * 4 + r;
      ((short*)ovh)[row * EMBED + h * HD + dt * 16 + rl] = f2bs(oacc[dt][r]);
    }
}

// spart [64 qt][64 bh][256][2] -> sfin [64 bh][256][2]
__global__ void stats_reduce(const float* __restrict__ sp, float* __restrict__ sf) {
  int bh = blockIdx.x, col = threadIdx.x;
  float m = -1e30f, l = 0.f;
  for (int qt = 0; qt < 64; qt++) {
    const float* p = sp + (((size_t)qt * 64 + bh) * 256 + col) * 2;
    float mi = p[0], li = p[1];
    float nm = fmaxf(m, mi);
    l = l * __expf(fminf(m - nm, 0.f)) + li * __expf(fminf(mi - nm, 0.f));
    m = nm;
  }
  float* o = sf + ((size_t)bh * 256 + col) * 2;
  o[0] = m;
  o[1] = fmaxf(l, 1e-20f);
}

__global__ void zero_f32(float* __restrict__ p, int n) {
  int i = blockIdx.x * 256 + threadIdx.x;
  if (i < n) p[i] = 0.f;
}

// ---------------------------------------------------------------------------
// Language-direction attention: per block (256 q rows, one bh):
// recompute S, P_l = exp(S - m_col)/l_col, atomically accumulate
// P_l^T @ val_v into olacc [B*NL][E] fp32.
// ---------------------------------------------------------------------------
__global__ __launch_bounds__(256) void attn_fwd_l(
    const bf16* __restrict__ q,   // [B*NV][E] pre-scaled
    const bf16* __restrict__ kk,  // [B*NL][E]
    const bf16* __restrict__ vv,  // [B*NV][E] val_v
    const float* __restrict__ sf, // [64 bh][256][2]
    float* __restrict__ olacc) {  // [B*NL][E] fp32, pre-zeroed
  __shared__ short k_lds[256 * 72];
  __shared__ short PT[256 * 40];
  __shared__ short vvT[64 * 40];
  __shared__ float sm[256];
  __shared__ float sl[256];
  const int tid = threadIdx.x, wave = tid >> 6, lane = tid & 63;
  const int chunk = blockIdx.x, bh = blockIdx.y;
  const int b = bh >> 4, h = bh & 15;
  const size_t krow0 = (size_t)b * NLTOK;
  const size_t qbase = (size_t)b * NVTOK + chunk * 256;
  const int rl = lane & 15, lg = lane >> 4;

#pragma unroll
  for (int it = 0; it < 8; it++) {
    int vvi = it * 256 + tid;
    int nl = vvi >> 3, c = vvi & 7;
    *(bf16x8*)&k_lds[nl * 72 + c * 8] =
        *(const bf16x8*)((const short*)kk + (krow0 + nl) * EMBED + h * HD + c * 8);
  }
  sm[tid] = sf[((size_t)bh * 256 + tid) * 2];
  sl[tid] = 1.0f / sf[((size_t)bh * 256 + tid) * 2 + 1];
  __syncthreads();

  floatx4 acc[4][4];
#pragma unroll
  for (int rt = 0; rt < 4; rt++)
#pragma unroll
    for (int dt = 0; dt < 4; dt++) acc[rt][dt] = (floatx4){0.f, 0.f, 0.f, 0.f};

  const int qrt = wave & 1, ctb = (wave >> 1) * 8;
  for (int qs = 0; qs < 8; qs++) {
    const short* qrow = (const short*)q + (qbase + qs * 32 + qrt * 16 + rl) * EMBED + h * HD;
    bf16x8 a0 = *(const bf16x8*)(qrow + lg * 8);
    bf16x8 a1 = *(const bf16x8*)(qrow + 32 + lg * 8);
    floatx4 s8[8];
#pragma unroll
    for (int i = 0; i < 8; i++) {
      int ct = ctb + i;
      bf16x8 b0 = *(const bf16x8*)&k_lds[(ct * 16 + rl) * 72 + lg * 8];
      bf16x8 b1 = *(const bf16x8*)&k_lds[(ct * 16 + rl) * 72 + 32 + lg * 8];
      floatx4 s = (floatx4){0.f, 0.f, 0.f, 0.f};
      s = MFMA(a0, b0, s);
      s = MFMA(a1, b1, s);
      s8[i] = s;
    }
    __syncthreads();  // previous iteration's PT/vvT reads complete
#pragma unroll
    for (int i = 0; i < 8; i++) {
      int col = (ctb + i) * 16 + rl;
      float m = sm[col], linv = sl[col];
#pragma unroll
      for (int r = 0; r < 4; r++)
        PT[col * 40 + qrt * 16 + lg * 4 + r] = f2bs(__expf(fminf(s8[i][r] - m, 0.f)) * linv);
    }
    {
      int qq = tid >> 3, c = tid & 7;
      bf16x8 vvv = *(const bf16x8*)((const short*)vv + (qbase + qs * 32 + qq) * EMBED + h * HD + c * 8);
      const short* vp = (const short*)&vvv;
#pragma unroll
      for (int j = 0; j < 8; j++) vvT[(c * 8 + j) * 40 + qq] = vp[j];
    }
    __syncthreads();
#pragma unroll
    for (int rt = 0; rt < 4; rt++) {
      bf16x8 af = *(const bf16x8*)&PT[(wave * 64 + rt * 16 + rl) * 40 + lg * 8];
#pragma unroll
      for (int dt = 0; dt < 4; dt++) {
        bf16x8 bfr = *(const bf16x8*)&vvT[(dt * 16 + rl) * 40 + lg * 8];
        acc[rt][dt] = MFMA(af, bfr, acc[rt][dt]);
      }
    }
  }
#pragma unroll
  for (int rt = 0; rt < 4; rt++)
#pragma unroll
    for (int dt = 0; dt < 4; dt++)
#pragma unroll
      for (int r = 0; r < 4; r++) {
        int nl = wave * 64 + rt * 16 + lg * 4 + r;
        int d = dt * 16 + rl;
        atomicAdd(&olacc[((size_t)b * NLTOK + nl) * EMBED + h * HD + d], acc[rt][dt][r]);
      }
}

__global__ void finalize_out_l(const float* __restrict__ olacc, bf16* __restrict__ olh) {
  int i = blockIdx.x * 256 + threadIdx.x;
  if (i < 1024 * 1024) olh[i] = __float2bfloat16(olacc[i]);
}

// ---------------------------------------------------------------------------
extern "C" void kernel_launch(void* const* d_in, const int* in_sizes, int n_in,
                              void* d_out, int out_size, void* d_ws, size_t ws_size,
                              hipStream_t stream) {
  (void)in_sizes; (void)n_in; (void)out_size; (void)ws_size;
  const void* v_raw = d_in[0];
  const void* l_raw = d_in[1];
  const int*  mask  = (const int*)d_in[2];
  const void* W_v2q = d_in[3];  const void* b_v2q = d_in[4];
  const void* W_l2k = d_in[5];  const void* b_l2k = d_in[6];
  const void* W_v2v = d_in[7];  const void* b_v2v = d_in[8];
  const void* W_l2v = d_in[9];  const void* b_l2v = d_in[10];
  const void* W_v2o = d_in[11]; const void* b_v2o = d_in[12];
  const void* W_l2o = d_in[13]; const void* b_l2o = d_in[14];

  char* ws = (char*)d_ws;
  size_t off = 0;
  auto alloc = [&](size_t bytes) -> void* {
    void* p = ws + off;
    off += (bytes + 255) & ~(size_t)255;
    return p;
  };
  int*  flag   = (int*)alloc(256);
  bf16* vb     = (bf16*)alloc((size_t)16777216 * 2);  // later aliased by ovh
  bf16* lb     = (bf16*)alloc((size_t)786432 * 2);
  bf16* bq     = (bf16*)alloc(2048);
  bf16* bk     = (bf16*)alloc(2048);
  bf16* bvv    = (bf16*)alloc(2048);
  bf16* bvl    = (bf16*)alloc(2048);
  bf16* bov    = (bf16*)alloc(2048);
  bf16* bol    = (bf16*)alloc(1536);
  bf16* Wt_v2q = (bf16*)alloc((size_t)1024 * 1024 * 2);
  bf16* Wt_l2k = (bf16*)alloc((size_t)1024 * 768 * 2);
  bf16* Wt_v2v = (bf16*)alloc((size_t)1024 * 1024 * 2);
  bf16* Wt_l2v = (bf16*)alloc((size_t)1024 * 768 * 2);
  bf16* Wt_v2o = (bf16*)alloc((size_t)1024 * 1024 * 2);
  bf16* Wt_l2o = (bf16*)alloc((size_t)768 * 1024 * 2);
  bf16* qb     = (bf16*)alloc((size_t)16384 * 1024 * 2);
  bf16* kb     = (bf16*)alloc((size_t)1024 * 1024 * 2);
  bf16* vvb    = (bf16*)alloc((size_t)16384 * 1024 * 2);
  bf16* vlb    = (bf16*)alloc((size_t)1024 * 1024 * 2);  // later aliased by olh
  bf16* vlT    = (bf16*)alloc((size_t)64 * 64 * 256 * 2);
  float* spart = (float*)alloc((size_t)64 * 64 * 256 * 2 * 4);  // later aliased by olacc
  float* sfin  = (float*)alloc((size_t)64 * 256 * 2 * 4);
  // aliases (lifetimes: vb dead after projections; vlb dead after
  // transpose_vl_heads; spart dead after stats_reduce)
  bf16*  ovh   = vb;
  float* olacc = spart;
  bf16*  olh   = vlb;

  detect_dtype<<<1, 256, 0, stream>>>((const unsigned*)v_raw, flag);

  convert_to_bf16_v4<<<16384, 256, 0, stream>>>(v_raw, vb, 4194304, flag);
  convert_to_bf16_v4<<<768, 256, 0, stream>>>(l_raw, lb, 196608, flag);

  BArgs ba;
  ba.src[0] = b_v2q; ba.dst[0] = bq;  ba.n[0] = 1024;
  ba.src[1] = b_l2k; ba.dst[1] = bk;  ba.n[1] = 1024;
  ba.src[2] = b_v2v; ba.dst[2] = bvv; ba.n[2] = 1024;
  ba.src[3] = b_l2v; ba.dst[3] = bvl; ba.n[3] = 1024;
  ba.src[4] = b_v2o; ba.dst[4] = bov; ba.n[4] = 1024;
  ba.src[5] = b_l2o; ba.dst[5] = bol; ba.n[5] = 768;
  convert_bias_all<<<dim3(4, 6), 256, 0, stream>>>(ba, flag);

  WTArgs wa;
  wa.src[0] = W_v2q; wa.dst[0] = Wt_v2q; wa.R[0] = 1024; wa.C[0] = 1024;
  wa.src[1] = W_l2k; wa.dst[1] = Wt_l2k; wa.R[1] = 768;  wa.C[1] = 1024;
  wa.src[2] = W_v2v; wa.dst[2] = Wt_v2v; wa.R[2] = 1024; wa.C[2] = 1024;
  wa.src[3] = W_l2v; wa.dst[3] = Wt_l2v; wa.R[3] = 768;  wa.C[3] = 1024;
  wa.src[4] = W_v2o; wa.dst[4] = Wt_v2o; wa.R[4] = 1024; wa.C[4] = 1024;
  wa.src[5] = W_l2o; wa.dst[5] = Wt_l2o; wa.R[5] = 1024; wa.C[5] = 768;
  convert_transpose_all<<<dim3(4096, 6), 256, 0, stream>>>(wa, flag);

  const int* bf16out = flag + 1;  // constant 0
  // projections (softmax scale folded into q)
  gemm_nt<<<dim3(128, 8), 256, 0, stream>>>(vb, Wt_v2q, bq, qb, 0, 16384, 1024, 1024, QSCALE, bf16out);
  gemm_nt<<<dim3(8, 8), 256, 0, stream>>>(lb, Wt_l2k, bk, kb, 0, 1024, 1024, 768, 1.0f, bf16out);
  gemm_nt<<<dim3(128, 8), 256, 0, stream>>>(vb, Wt_v2v, bvv, vvb, 0, 16384, 1024, 1024, 1.0f, bf16out);
  gemm_nt<<<dim3(8, 8), 256, 0, stream>>>(lb, Wt_l2v, bvl, vlb, 0, 1024, 1024, 768, 1.0f, bf16out);
  transpose_vl_heads<<<4096, 256, 0, stream>>>(vlb, vlT);

  // attention (vb is dead now; ovh aliases it)
  attn_fwd_v<<<dim3(64, 64), 256, 0, stream>>>(qb, kb, vlT, mask, ovh, spart);
  stats_reduce<<<64, 256, 0, stream>>>(spart, sfin);
  zero_f32<<<4096, 256, 0, stream>>>(olacc, 1024 * 1024);  // spart dead; olacc aliases it
  attn_fwd_l<<<dim3(16, 64), 256, 0, stream>>>(qb, kb, vvb, sfin, olacc);
  finalize_out_l<<<4096, 256, 0, stream>>>(olacc, olh);    // olh aliases vlb (dead)

  // output projections straight into d_out (dtype per flag)
  gemm_nt<<<dim3(128, 8), 256, 0, stream>>>(ovh, Wt_v2o, bov, d_out, 0, 16384, 1024, 1024, 1.0f, flag);
  gemm_nt<<<dim3(8, 6), 256, 0, stream>>>(olh, Wt_l2o, bol, d_out, 16777216LL, 1024, 768, 1024, 1.0f, flag);
}